// Round 5
// baseline (1012.511 us; speedup 1.0000x reference)
//
#include <hip/hip_runtime.h>
#include <math.h>

#define BB 8
#define NN 4096
#define UU 128
#define BM 128      // rows per block tile
#define BK 64       // K-chunk (neighbor dim)
#define NXCD 8      // MI355X: blockIdx round-robins XCDs (bid % 8)

typedef float  f4_t   __attribute__((ext_vector_type(4)));
typedef float  f32x4  __attribute__((ext_vector_type(4)));
typedef unsigned int u32x4 __attribute__((ext_vector_type(4)));
typedef unsigned int u32x2 __attribute__((ext_vector_type(2)));
typedef short  bf16x8 __attribute__((ext_vector_type(8)));

// fp32 -> bf16 by truncation: EXACT for adj values {0.0, 1.0}
static __device__ __forceinline__ unsigned int pack2_trunc(float lo, float hi) {
    return (__float_as_uint(hi) & 0xFFFF0000u) | (__float_as_uint(lo) >> 16);
}
// fp32 -> bf16 round-to-nearest-even (for x / h1)
static __device__ __forceinline__ unsigned int bf16_rne1(float f) {
    unsigned int u = __float_as_uint(f);
    return (u + 0x7FFFu + ((u >> 16) & 1u)) >> 16;
}
static __device__ __forceinline__ unsigned int pack2_rne(float lo, float hi) {
    return bf16_rne1(lo) | (bf16_rne1(hi) << 16);
}

// ---------------------------------------------------------------------------
// Prologue: x fp32 [B,N,U] -> bf16 (RNE). 4.19M floats, 8/thread.
// ---------------------------------------------------------------------------
__global__ __launch_bounds__(256) void cvt_bf16_kernel(
    const float* __restrict__ in, unsigned short* __restrict__ outb)
{
    const size_t i = ((size_t)blockIdx.x * 256 + threadIdx.x) * 8;
    const f4_t v0 = *(const f4_t*)(in + i);
    const f4_t v1 = *(const f4_t*)(in + i + 4);
    u32x4 o;
    o.x = pack2_rne(v0[0], v0[1]);
    o.y = pack2_rne(v0[2], v0[3]);
    o.z = pack2_rne(v1[0], v1[1]);
    o.w = pack2_rne(v1[2], v1[3]);
    *(u32x4*)(outb + i) = o;
}

// ---------------------------------------------------------------------------
// One hop, fully fused: C[b, i0:i0+128, :] = swish( (adj[b] @ H[b]) @ W + bias )
//   - adj streamed fp32->bf16 (exact), nontemporal (read-once, keep H in L2)
//   - H bf16 [N,U], staged transposed into LDS for the MFMA B-operand
//   - mfma_f32_16x16x32_bf16; 8 waves in a 2(M)x4(N) grid, 64x32 per wave
//   - epilogue: C-tile (=hn rows, fp32) -> LDS -> register-blocked W-gemm
//     + swish, written bf16 (hop1) or fp32 (hop2)
// Grid: 256 blocks = 8 batches x 32 M-tiles; batch = bid%8 = XCD (L2 affinity
// for H; perf heuristic only). 512 threads.
// ---------------------------------------------------------------------------
template<int OUT_BF16>
__global__ __launch_bounds__(512) void hop_kernel(
    const float* __restrict__ adj,
    const unsigned short* __restrict__ hsrc,   // bf16 [B,N,U]
    const float* __restrict__ Wm,
    const float* __restrict__ bias,
    void* __restrict__ dst)
{
    // union'd LDS: during K-loop  -> sA [128][72] bf16 + sH [128(c)][72(k)] bf16
    //              during epilogue-> sHN [128][132] fp32 (67584 B total)
    __shared__ __align__(16) char smem[128 * 132 * 4];
    short* sA  = (short*)smem;             // A tile, row-major, +8 bf16 pad
    short* sH  = sA + 128 * 72;            // H tile, TRANSPOSED [c][k], padded
    float* sHN = (float*)smem;             // hn tile (aliases; phase-separated)

    const int t  = threadIdx.x;
    const int b  = blockIdx.x & (NXCD - 1);        // batch == XCD
    const int i0 = (blockIdx.x >> 3) * BM;

    const float* ab          = adj  + (size_t)b * NN * NN;
    const unsigned short* hb = hsrc + (size_t)b * NN * UU;

    // A staging: thread -> (row ar, 16-float quad aq). Coalesced 64B/thread.
    const int ar = t >> 2, aq = t & 3;
    const int sa_off = ar * 72 + aq * 16;
    // H staging: thread -> (k = hk, 16 channels from hc0). Reads coalesced
    // across hk within a k-row group; writes transpose into [c][k].
    const int hk = t & 63, hc0 = (t >> 6) * 16;

    // wave/fragment coords
    const int wid = t >> 6, lane = t & 63;
    const int wm = wid >> 2;            // 0..1 : M 64-row half
    const int wn = wid & 3;             // 0..3 : N 32-col quarter
    const int fr = lane & 15, fq = lane >> 4;

    f32x4 acc[4][2];
    #pragma unroll
    for (int m = 0; m < 4; ++m)
        #pragma unroll
        for (int n = 0; n < 2; ++n)
            acc[m][n] = (f32x4){0.f, 0.f, 0.f, 0.f};

    // fragment LDS element offsets (k-base added per k-step)
    int aoff[4], boff[2];
    #pragma unroll
    for (int m = 0; m < 4; ++m) aoff[m] = (wm * 64 + m * 16 + fr) * 72 + fq * 8;
    #pragma unroll
    for (int n = 0; n < 2; ++n) boff[n] = (wn * 32 + n * 16 + fr) * 72 + fq * 8;

    f4_t  areg[4];
    u32x4 hreg0, hreg1;

    auto LOAD = [&](int k0) {
        const f4_t* ap = (const f4_t*)(ab + (size_t)(i0 + ar) * NN + k0) + aq * 4;
        areg[0] = __builtin_nontemporal_load(ap + 0);
        areg[1] = __builtin_nontemporal_load(ap + 1);
        areg[2] = __builtin_nontemporal_load(ap + 2);
        areg[3] = __builtin_nontemporal_load(ap + 3);
        const u32x4* hp = (const u32x4*)(hb + (size_t)(k0 + hk) * UU + hc0);
        hreg0 = hp[0];
        hreg1 = hp[1];
    };

    auto STORE_LDS = [&]() {
        u32x4 lo, hi;
        lo.x = pack2_trunc(areg[0][0], areg[0][1]);
        lo.y = pack2_trunc(areg[0][2], areg[0][3]);
        lo.z = pack2_trunc(areg[1][0], areg[1][1]);
        lo.w = pack2_trunc(areg[1][2], areg[1][3]);
        hi.x = pack2_trunc(areg[2][0], areg[2][1]);
        hi.y = pack2_trunc(areg[2][2], areg[2][3]);
        hi.z = pack2_trunc(areg[3][0], areg[3][1]);
        hi.w = pack2_trunc(areg[3][2], areg[3][3]);
        *(u32x4*)&sA[sa_off]     = lo;
        *(u32x4*)&sA[sa_off + 8] = hi;
        unsigned short hv[16];
        *(u32x4*)&hv[0] = hreg0;
        *(u32x4*)&hv[8] = hreg1;
        #pragma unroll
        for (int j = 0; j < 16; ++j)           // transpose: [k][c] -> [c][k]
            sH[(hc0 + j) * 72 + hk] = (short)hv[j];
    };

    LOAD(0);
    #pragma unroll 1
    for (int c = 0; c < NN / BK; ++c) {
        STORE_LDS();                           // waits on own vmcnt only
        __syncthreads();
        if (c < NN / BK - 1) LOAD((c + 1) * BK);   // issue early, hide HBM
        #pragma unroll
        for (int ks = 0; ks < 2; ++ks) {
            bf16x8 av[4], bv[2];
            const int kb = ks * 32;
            #pragma unroll
            for (int m = 0; m < 4; ++m) av[m] = *(const bf16x8*)&sA[aoff[m] + kb];
            #pragma unroll
            for (int n = 0; n < 2; ++n) bv[n] = *(const bf16x8*)&sH[boff[n] + kb];
            #pragma unroll
            for (int m = 0; m < 4; ++m)
                #pragma unroll
                for (int n = 0; n < 2; ++n)
                    acc[m][n] = __builtin_amdgcn_mfma_f32_16x16x32_bf16(
                        av[m], bv[n], acc[m][n], 0, 0, 0);
        }
        __syncthreads();
    }

    // ---- epilogue: hn tile -> LDS (layout verified m89/m91: row=(lane>>4)*4+reg, col=lane&15)
    #pragma unroll
    for (int m = 0; m < 4; ++m)
        #pragma unroll
        for (int n = 0; n < 2; ++n)
            #pragma unroll
            for (int r = 0; r < 4; ++r)
                sHN[(wm * 64 + m * 16 + fq * 4 + r) * 132
                    + (wn * 32 + n * 16 + fr)] = acc[m][n][r];
    __syncthreads();

    // ---- register-blocked W-gemm + swish (proven round-0 structure) ----
    const int cg = t & 31;                     // output cols cg*4 .. +3
    const int r0 = (t >> 5) * 8;               // 8 rows per thread
    float aw[8][4];
    #pragma unroll
    for (int r = 0; r < 8; ++r)
        #pragma unroll
        for (int cxx = 0; cxx < 4; ++cxx) aw[r][cxx] = 0.f;

    const f4_t* W4 = (const f4_t*)Wm;
    #pragma unroll 4
    for (int k = 0; k < UU; k += 4) {
        const f4_t w0 = W4[(k + 0) * 32 + cg];
        const f4_t w1 = W4[(k + 1) * 32 + cg];
        const f4_t w2 = W4[(k + 2) * 32 + cg];
        const f4_t w3 = W4[(k + 3) * 32 + cg];
        #pragma unroll
        for (int r = 0; r < 8; ++r) {
            const f4_t sv = *(const f4_t*)&sHN[(r0 + r) * 132 + k];
            aw[r][0] += sv[0]*w0[0] + sv[1]*w1[0] + sv[2]*w2[0] + sv[3]*w3[0];
            aw[r][1] += sv[0]*w0[1] + sv[1]*w1[1] + sv[2]*w2[1] + sv[3]*w3[1];
            aw[r][2] += sv[0]*w0[2] + sv[1]*w1[2] + sv[2]*w2[2] + sv[3]*w3[2];
            aw[r][3] += sv[0]*w0[3] + sv[1]*w1[3] + sv[2]*w2[3] + sv[3]*w3[3];
        }
    }

    const f4_t bb4 = ((const f4_t*)bias)[cg];
    #pragma unroll
    for (int r = 0; r < 8; ++r) {
        const size_t row = (size_t)b * NN + i0 + r0 + r;
        float v, o0, o1, o2, o3;
        v = aw[r][0] + bb4[0]; o0 = v / (1.f + expf(-v));
        v = aw[r][1] + bb4[1]; o1 = v / (1.f + expf(-v));
        v = aw[r][2] + bb4[2]; o2 = v / (1.f + expf(-v));
        v = aw[r][3] + bb4[3]; o3 = v / (1.f + expf(-v));
        if (OUT_BF16) {
            u32x2 p;
            p.x = pack2_rne(o0, o1);
            p.y = pack2_rne(o2, o3);
            *(u32x2*)((unsigned short*)dst + row * UU + cg * 4) = p;
        } else {
            f4_t o = {o0, o1, o2, o3};
            *(f4_t*)((float*)dst + row * UU + cg * 4) = o;
        }
    }
}

// ---------------------------------------------------------------------------
extern "C" void kernel_launch(void* const* d_in, const int* in_sizes, int n_in,
                              void* d_out, int out_size, void* d_ws, size_t ws_size,
                              hipStream_t stream)
{
    const float* x    = (const float*)d_in[0];   // [B,N,U] fp32
    const float* adj  = (const float*)d_in[1];   // [B,N,N] binary fp32
    const float* Wm   = (const float*)d_in[2];   // [U,U]
    const float* bias = (const float*)d_in[3];   // [U]
    float* out = (float*)d_out;                  // [B,N,U] fp32

    unsigned short* xb  = (unsigned short*)d_ws;           // 8 MiB bf16 x
    unsigned short* h1b = xb + (size_t)BB * NN * UU;       // 8 MiB bf16 h1

    // x -> bf16 (RNE)
    cvt_bf16_kernel<<<(BB * NN * UU) / (256 * 8), 256, 0, stream>>>(x, xb);

    // Hop 1: swish((adj@xb)@W + b) -> h1 (bf16)
    hop_kernel<1><<<BB * (NN / BM), 512, 0, stream>>>(adj, xb, Wm, bias, (void*)h1b);

    // Hop 2: swish((adj@h1b)@W + b) -> out (fp32)
    hop_kernel<0><<<BB * (NN / BM), 512, 0, stream>>>(adj, h1b, Wm, bias, (void*)out);
}

// Round 7
// 974.636 us; speedup vs baseline: 1.0389x; 1.0389x over previous
//
#include <hip/hip_runtime.h>
#include <math.h>

#define BB 8
#define NN 4096
#define UU 128
#define BM 128      // rows per block tile (round-5 geometry, verified correct)
#define BK 64       // K-chunk (neighbor dim)
#define NXCD 8      // MI355X: blockIdx round-robins XCDs (bid % 8)

typedef float  f4_t   __attribute__((ext_vector_type(4)));
typedef float  f32x4  __attribute__((ext_vector_type(4)));
typedef unsigned int u32x4 __attribute__((ext_vector_type(4)));
typedef unsigned int u32x2 __attribute__((ext_vector_type(2)));
typedef short  bf16x8 __attribute__((ext_vector_type(8)));

// Raw barrier (NO implicit vmcnt(0) drain -- this is the entire point):
// prefetched global loads stay in flight across it. lgkmcnt(0) with memory
// clobber = my LDS ops done & ordered; sched_barrier(0) = nothing floats
// across the barrier in the scheduler.
#define WAITL0  asm volatile("s_waitcnt lgkmcnt(0)" ::: "memory")
#define RAWBAR  do { WAITL0; __builtin_amdgcn_sched_barrier(0); \
                     __builtin_amdgcn_s_barrier();              \
                     __builtin_amdgcn_sched_barrier(0); } while (0)

// fp32 -> bf16 truncation: EXACT for adj values {0.0, 1.0}
static __device__ __forceinline__ unsigned int pack2_trunc(float lo, float hi) {
    return (__float_as_uint(hi) & 0xFFFF0000u) | (__float_as_uint(lo) >> 16);
}
// fp32 -> bf16 RNE (for x / h1)
static __device__ __forceinline__ unsigned int bf16_rne1(float f) {
    unsigned int u = __float_as_uint(f);
    return (u + 0x7FFFu + ((u >> 16) & 1u)) >> 16;
}
static __device__ __forceinline__ unsigned int pack2_rne(float lo, float hi) {
    return bf16_rne1(lo) | (bf16_rne1(hi) << 16);
}

// ---------------------------------------------------------------------------
// Prologue: x fp32 [B,N,U] -> bf16 (RNE). 4.19M floats, 8/thread.
// ---------------------------------------------------------------------------
__global__ __launch_bounds__(256) void cvt_bf16_kernel(
    const float* __restrict__ in, unsigned short* __restrict__ outb)
{
    const size_t i = ((size_t)blockIdx.x * 256 + threadIdx.x) * 8;
    const f4_t v0 = *(const f4_t*)(in + i);
    const f4_t v1 = *(const f4_t*)(in + i + 4);
    u32x4 o;
    o.x = pack2_rne(v0[0], v0[1]);
    o.y = pack2_rne(v0[2], v0[3]);
    o.z = pack2_rne(v1[0], v1[1]);
    o.w = pack2_rne(v1[2], v1[3]);
    *(u32x4*)(outb + i) = o;
}

// ---------------------------------------------------------------------------
// One hop: C[b, i0:i0+128, :] = swish( (adj[b] @ H[b]) @ W + bias )
// Geometry IDENTICAL to the verified round-5 kernel (512 thr, 8 waves 2Mx4N,
// same staging maps, fragment offsets, epilogue, W-gemm). Delta vs round 5 is
// ONLY the K-loop schedule: LDS double-buffer + 2 register prefetch sets +
// RAW barriers (no vmcnt drain) so each chunk's loads ride under the previous
// chunk's MFMA instead of being drained at every __syncthreads.
// Grid 256 = 8 batches x 32 M-tiles; batch = bid%8 = XCD (H L2-affinity).
// ---------------------------------------------------------------------------
template<int OUT_BF16>
__global__ __launch_bounds__(512) void hop_kernel(
    const float* __restrict__ adj,
    const unsigned short* __restrict__ hsrc,   // bf16 [B,N,U]
    const float* __restrict__ Wm,
    const float* __restrict__ bias,
    void* __restrict__ dst)
{
    // K-loop: sA[128][72]x2 + sH[128c][72k]x2 bf16 = 73728 B
    // epilogue: sHN[128][132] fp32 = 67584 B (aliases, phase-separated)
    __shared__ __align__(16) char smem[73728];
    short* sA0 = (short*)smem;
    short* sA1 = sA0 + 128 * 72;
    short* sH0 = sA1 + 128 * 72;
    short* sH1 = sH0 + 128 * 72;
    float* sHN = (float*)smem;

    const int t  = threadIdx.x;
    const int b  = blockIdx.x & (NXCD - 1);        // batch == XCD
    const int i0 = (blockIdx.x >> 3) * BM;

    const float* ab          = adj  + (size_t)b * NN * NN;
    const unsigned short* hb = hsrc + (size_t)b * NN * UU;

    // A staging (as round 5): thread -> (row ar, 16-float quad aq)
    const int ar = t >> 2, aq = t & 3;
    const int sa_off = ar * 72 + aq * 16;
    // H staging (as round 5): thread -> (k row hk, 16 channels from hc0)
    const int hk = t & 63, hc0 = (t >> 6) * 16;

    // wave/fragment coords (as round 5): 8 waves, 2(M) x 4(N)
    const int wid = t >> 6, lane = t & 63;
    const int wm = wid >> 2;            // 0..1 : M 64-row half
    const int wn = wid & 3;             // 0..3 : N 32-col quarter
    const int fr = lane & 15, fq = lane >> 4;

    f32x4 acc[4][2];
    #pragma unroll
    for (int m = 0; m < 4; ++m)
        #pragma unroll
        for (int n = 0; n < 2; ++n)
            acc[m][n] = (f32x4){0.f, 0.f, 0.f, 0.f};

    int aoff[4], boff[2];
    #pragma unroll
    for (int m = 0; m < 4; ++m) aoff[m] = (wm * 64 + m * 16 + fr) * 72 + fq * 8;
    #pragma unroll
    for (int n = 0; n < 2; ++n) boff[n] = (wn * 32 + n * 16 + fr) * 72 + fq * 8;

    f4_t  areg0[4], areg1[4];
    u32x4 hreg0[2], hreg1[2];

    auto LOAD = [&](f4_t* areg, u32x4* hreg, int k0) {
        const f4_t* ap = (const f4_t*)(ab + (size_t)(i0 + ar) * NN + k0) + aq * 4;
        areg[0] = __builtin_nontemporal_load(ap + 0);
        areg[1] = __builtin_nontemporal_load(ap + 1);
        areg[2] = __builtin_nontemporal_load(ap + 2);
        areg[3] = __builtin_nontemporal_load(ap + 3);
        const u32x4* hp = (const u32x4*)(hb + (size_t)(k0 + hk) * UU + hc0);
        hreg[0] = hp[0];
        hreg[1] = hp[1];
    };

    auto STORE = [&](short* sA, short* sH, const f4_t* areg, const u32x4* hreg) {
        u32x4 lo, hi;
        lo.x = pack2_trunc(areg[0][0], areg[0][1]);
        lo.y = pack2_trunc(areg[0][2], areg[0][3]);
        lo.z = pack2_trunc(areg[1][0], areg[1][1]);
        lo.w = pack2_trunc(areg[1][2], areg[1][3]);
        hi.x = pack2_trunc(areg[2][0], areg[2][1]);
        hi.y = pack2_trunc(areg[2][2], areg[2][3]);
        hi.z = pack2_trunc(areg[3][0], areg[3][1]);
        hi.w = pack2_trunc(areg[3][2], areg[3][3]);
        *(u32x4*)&sA[sa_off]     = lo;
        *(u32x4*)&sA[sa_off + 8] = hi;
        unsigned short hv[16];
        *(u32x4*)&hv[0] = hreg[0];
        *(u32x4*)&hv[8] = hreg[1];
        #pragma unroll
        for (int j = 0; j < 16; ++j)            // transpose: [k][c] -> [c][k]
            sH[(hc0 + j) * 72 + hk] = (short)hv[j];
    };

    auto MMA = [&](const short* sA, const short* sH) {
        #pragma unroll
        for (int ks = 0; ks < 2; ++ks) {
            bf16x8 av[4], bv[2];
            const int kb = ks * 32;
            #pragma unroll
            for (int m = 0; m < 4; ++m) av[m] = *(const bf16x8*)&sA[aoff[m] + kb];
            #pragma unroll
            for (int n = 0; n < 2; ++n) bv[n] = *(const bf16x8*)&sH[boff[n] + kb];
            #pragma unroll
            for (int m = 0; m < 4; ++m)
                #pragma unroll
                for (int n = 0; n < 2; ++n)
                    acc[m][n] = __builtin_amdgcn_mfma_f32_16x16x32_bf16(
                        av[m], bv[n], acc[m][n], 0, 0, 0);
        }
    };

    LOAD(areg0, hreg0, 0);
    LOAD(areg1, hreg1, BK);
    #pragma unroll 1
    for (int c = 0; c < NN / BK; c += 2) {
        // compiler auto-inserts a COUNTED vmcnt here (set-0 regs only);
        // set-1 loads stay in flight across the raw barrier.
        STORE(sA0, sH0, areg0, hreg0);
        if (c + 2 < NN / BK) LOAD(areg0, hreg0, (c + 2) * BK);
        RAWBAR;          // buf0 writes visible; prev MMA1 reads drained
        MMA(sA0, sH0);
        STORE(sA1, sH1, areg1, hreg1);
        if (c + 3 < NN / BK) LOAD(areg1, hreg1, (c + 3) * BK);
        RAWBAR;          // buf1 writes visible; MMA0 reads drained
        MMA(sA1, sH1);
    }
    __syncthreads();     // full drain once, before aliasing smem as sHN

    // ---- epilogue: hn tile -> LDS (C/D layout m89/m91: row=fq*4+r, col=fr)
    #pragma unroll
    for (int m = 0; m < 4; ++m)
        #pragma unroll
        for (int n = 0; n < 2; ++n)
            #pragma unroll
            for (int r = 0; r < 4; ++r)
                sHN[(wm * 64 + m * 16 + fq * 4 + r) * 132
                    + (wn * 32 + n * 16 + fr)] = acc[m][n][r];
    __syncthreads();

    // ---- register-blocked W-gemm + swish (round-0/5 proven structure) ----
    const int cg = t & 31;                      // output cols cg*4 .. +3
    const int r0 = (t >> 5) * 8;                // 8 rows per thread
    float aw[8][4];
    #pragma unroll
    for (int r = 0; r < 8; ++r)
        #pragma unroll
        for (int cc = 0; cc < 4; ++cc) aw[r][cc] = 0.f;

    const f4_t* W4 = (const f4_t*)Wm;
    #pragma unroll 4
    for (int k = 0; k < UU; k += 4) {
        const f4_t w0 = W4[(k + 0) * 32 + cg];
        const f4_t w1 = W4[(k + 1) * 32 + cg];
        const f4_t w2 = W4[(k + 2) * 32 + cg];
        const f4_t w3 = W4[(k + 3) * 32 + cg];
        #pragma unroll
        for (int r = 0; r < 8; ++r) {
            const f4_t sv = *(const f4_t*)&sHN[(r0 + r) * 132 + k];
            aw[r][0] += sv[0]*w0[0] + sv[1]*w1[0] + sv[2]*w2[0] + sv[3]*w3[0];
            aw[r][1] += sv[0]*w0[1] + sv[1]*w1[1] + sv[2]*w2[1] + sv[3]*w3[1];
            aw[r][2] += sv[0]*w0[2] + sv[1]*w1[2] + sv[2]*w2[2] + sv[3]*w3[2];
            aw[r][3] += sv[0]*w0[3] + sv[1]*w1[3] + sv[2]*w2[3] + sv[3]*w3[3];
        }
    }

    const f4_t bb4 = ((const f4_t*)bias)[cg];
    #pragma unroll
    for (int r = 0; r < 8; ++r) {
        const size_t row = (size_t)b * NN + i0 + r0 + r;
        float v, o0, o1, o2, o3;
        v = aw[r][0] + bb4[0]; o0 = v / (1.f + expf(-v));
        v = aw[r][1] + bb4[1]; o1 = v / (1.f + expf(-v));
        v = aw[r][2] + bb4[2]; o2 = v / (1.f + expf(-v));
        v = aw[r][3] + bb4[3]; o3 = v / (1.f + expf(-v));
        if (OUT_BF16) {
            u32x2 p;
            p.x = pack2_rne(o0, o1);
            p.y = pack2_rne(o2, o3);
            *(u32x2*)((unsigned short*)dst + row * UU + cg * 4) = p;
        } else {
            f4_t o = {o0, o1, o2, o3};
            *(f4_t*)((float*)dst + row * UU + cg * 4) = o;
        }
    }
}

// ---------------------------------------------------------------------------
extern "C" void kernel_launch(void* const* d_in, const int* in_sizes, int n_in,
                              void* d_out, int out_size, void* d_ws, size_t ws_size,
                              hipStream_t stream)
{
    const float* x    = (const float*)d_in[0];   // [B,N,U] fp32
    const float* adj  = (const float*)d_in[1];   // [B,N,N] binary fp32
    const float* Wm   = (const float*)d_in[2];   // [U,U]
    const float* bias = (const float*)d_in[3];   // [U]
    float* out = (float*)d_out;                  // [B,N,U] fp32

    unsigned short* xb  = (unsigned short*)d_ws;           // 8 MiB bf16 x
    unsigned short* h1b = xb + (size_t)BB * NN * UU;       // 8 MiB bf16 h1

    cvt_bf16_kernel<<<(BB * NN * UU) / (256 * 8), 256, 0, stream>>>(x, xb);

    // Hop 1: swish((adj@xb)@W + b) -> h1 (bf16)
    hop_kernel<1><<<BB * (NN / BM), 512, 0, stream>>>(adj, xb, Wm, bias, (void*)h1b);

    // Hop 2: swish((adj@h1b)@W + b) -> out (fp32)
    hop_kernel<0><<<BB * (NN / BM), 512, 0, stream>>>(adj, h1b, Wm, bias, (void*)out);
}

// Round 8
// 922.237 us; speedup vs baseline: 1.0979x; 1.0568x over previous
//
#include <hip/hip_runtime.h>
#include <math.h>

#define BB 8
#define NN 4096
#define UU 128
#define BM 128      // rows per block tile
#define BK 64       // K-chunk (neighbor dim)
#define NXCD 8      // MI355X: blockIdx round-robins XCDs (bid % 8)

typedef float  f4_t   __attribute__((ext_vector_type(4)));
typedef float  f32x4  __attribute__((ext_vector_type(4)));
typedef unsigned int u32x4 __attribute__((ext_vector_type(4)));
typedef unsigned int u32x2 __attribute__((ext_vector_type(2)));
typedef short  bf16x8 __attribute__((ext_vector_type(8)));

// Counted vmcnt wait (literal N) -- never drain to 0 in the main loop.
#define VMW(n) do { asm volatile("s_waitcnt vmcnt(" #n ")" ::: "memory"); \
                    __builtin_amdgcn_sched_barrier(0); } while (0)
#define LG0    do { asm volatile("s_waitcnt lgkmcnt(0)" ::: "memory"); \
                    __builtin_amdgcn_sched_barrier(0); } while (0)
// Raw barrier: no implicit vmcnt drain; DMA queue survives it.
#define RAWBAR do { LG0; __builtin_amdgcn_s_barrier(); \
                    __builtin_amdgcn_sched_barrier(0); } while (0)

// fp32 -> bf16 truncation: EXACT for adj values {0.0, 1.0}
static __device__ __forceinline__ unsigned int pack2_trunc(float lo, float hi) {
    return (__float_as_uint(hi) & 0xFFFF0000u) | (__float_as_uint(lo) >> 16);
}
// fp32 -> bf16 RNE (for x / h1)
static __device__ __forceinline__ unsigned int bf16_rne1(float f) {
    unsigned int u = __float_as_uint(f);
    return (u + 0x7FFFu + ((u >> 16) & 1u)) >> 16;
}
static __device__ __forceinline__ unsigned int pack2_rne(float lo, float hi) {
    return bf16_rne1(lo) | (bf16_rne1(hi) << 16);
}

// ---------------------------------------------------------------------------
// Prologue: x fp32 [B,N,U] -> bf16 (RNE). 4.19M floats, 8/thread.
// ---------------------------------------------------------------------------
__global__ __launch_bounds__(256) void cvt_bf16_kernel(
    const float* __restrict__ in, unsigned short* __restrict__ outb)
{
    const size_t i = ((size_t)blockIdx.x * 256 + threadIdx.x) * 8;
    const f4_t v0 = *(const f4_t*)(in + i);
    const f4_t v1 = *(const f4_t*)(in + i + 4);
    u32x4 o;
    o.x = pack2_rne(v0[0], v0[1]);
    o.y = pack2_rne(v0[2], v0[3]);
    o.z = pack2_rne(v1[0], v1[1]);
    o.w = pack2_rne(v1[2], v1[3]);
    *(u32x4*)(outb + i) = o;
}

// ---------------------------------------------------------------------------
// One hop: C[b, i0:i0+128, :] = swish( (adj[b] @ H[b]) @ W + bias )
// Round-8 schedule: adj staged by global_load_lds (fp32, 3 LDS buffers,
// ~64-96 KB in flight per CU -- Little's law needs ~9 KB for full HBM BW;
// register prefetch capped us at ~2 KB = the 1.7 TB/s wall of rounds 0-7).
// Source pre-swizzled per-lane (quad s -> s ^ (row&15)); fragment reads XOR
// the same involution => conflict-free. fp32->bf16 conversion at frag read.
// H: reg-staged (L2-resident), XOR-swizzled single LDS buffer.
// Counted vmcnt(10/6/0); raw barriers (never drain the DMA queue).
// Geometry/epilogue/W-gemm identical to verified round-5/7.
// ---------------------------------------------------------------------------
template<int OUT_BF16>
__global__ __launch_bounds__(512, 1) void hop_kernel(
    const float* __restrict__ adj,
    const unsigned short* __restrict__ hsrc,   // bf16 [B,N,U]
    const float* __restrict__ Wm,
    const float* __restrict__ bias,
    void* __restrict__ dst)
{
    // bufA: 3 x [128 rows][64 k] fp32 = 3 x 32 KiB (DMA dest, linear)
    // sH:   [128 c][64 k + 8 pad] bf16 = 18 KiB (single buffer)
    // sHN:  [128][132] fp32 = 66 KiB epilogue tile, aliases bufA region
    __shared__ __align__(16) char smem[116736];
    short* sH  = (short*)(smem + 98304);
    float* sHN = (float*)smem;

    const int t  = threadIdx.x;
    const int b  = blockIdx.x & (NXCD - 1);        // batch == XCD
    const int i0 = (blockIdx.x >> 3) * BM;

    const float* ab          = adj  + (size_t)b * NN * NN;
    const unsigned short* hb = hsrc + (size_t)b * NN * UU;

    // H staging: thread -> (k row hk, 16 channels from hc0)
    const int hk = t & 63, hc0 = (t >> 6) * 16;

    // wave/fragment coords: 8 waves, 2(M) x 4(N)
    const int wid = t >> 6, lane = t & 63;
    const int wm = wid >> 2;            // 0..1 : M 64-row half
    const int wn = wid & 3;             // 0..3 : N 32-col quarter
    const int fr = lane & 15, fq = lane >> 4;

    f32x4 acc[4][2];
    #pragma unroll
    for (int m = 0; m < 4; ++m)
        #pragma unroll
        for (int n = 0; n < 2; ++n)
            acc[m][n] = (f32x4){0.f, 0.f, 0.f, 0.f};

    // --- A DMA: 32 windows of 1 KiB; wave wid owns windows wid*4..wid*4+3.
    // lds byte (linear) = W*1024 + lane*16 -> (row = W*4 + lane/16,
    // phys quad = lane&15). Source fetches LOGICAL quad (phys ^ (row&15)).
    auto ISSUE_A = [&](int buf, int k0) {
        char* dstbase = smem + (size_t)buf * 32768;
        #pragma unroll
        for (int i = 0; i < 4; ++i) {
            const int W = wid * 4 + i;
            const int r = (W << 2) + (lane >> 4);
            const int q = (lane & 15) ^ (r & 15);
            const float* src = ab + (size_t)(i0 + r) * NN + k0 + (q << 2);
            __builtin_amdgcn_global_load_lds(
                (const __attribute__((address_space(1))) unsigned int*)src,
                (__attribute__((address_space(3))) unsigned int*)(dstbase + W * 1024),
                16, 0, 0);
        }
    };

    u32x4 hA[2], hB[2];
    auto LOAD_H = [&](u32x4* h, int k0) {
        const u32x4* hp = (const u32x4*)(hb + (size_t)(k0 + hk) * UU + hc0);
        h[0] = hp[0];
        h[1] = hp[1];
    };
    // H write swizzle: quad (hk>>3) stored at (hk>>3) ^ (c&7); reads undo it.
    auto STORE_H = [&](const u32x4* h) {
        unsigned short hv[16];
        *(u32x4*)&hv[0] = h[0];
        *(u32x4*)&hv[8] = h[1];
        const int qs = hk >> 3, kl = hk & 7;
        #pragma unroll
        for (int j = 0; j < 16; ++j) {
            const int c = hc0 + j;
            sH[c * 72 + ((qs ^ (c & 7)) << 3) + kl] = (short)hv[j];
        }
    };

    auto MMA = [&](int buf) {
        const float* bA = (const float*)(smem + (size_t)buf * 32768);
        #pragma unroll
        for (int ks = 0; ks < 2; ++ks) {
            bf16x8 av[4], bv[2];
            #pragma unroll
            for (int m = 0; m < 4; ++m) {
                const int row = wm * 64 + m * 16 + fr;
                const int sw  = row & 15;
                const int q0  = ks * 8 + fq * 2;
                const f4_t x0 = *(const f4_t*)(bA + row * 64 + (((q0 + 0) ^ sw) << 2));
                const f4_t x1 = *(const f4_t*)(bA + row * 64 + (((q0 + 1) ^ sw) << 2));
                u32x4 pk;
                pk.x = pack2_trunc(x0[0], x0[1]);
                pk.y = pack2_trunc(x0[2], x0[3]);
                pk.z = pack2_trunc(x1[0], x1[1]);
                pk.w = pack2_trunc(x1[2], x1[3]);
                av[m] = *(bf16x8*)&pk;
            }
            #pragma unroll
            for (int n = 0; n < 2; ++n) {
                const int c = wn * 32 + n * 16 + fr;
                bv[n] = *(const bf16x8*)&sH[c * 72 + (((ks * 4 + fq) ^ (c & 7)) << 3)];
            }
            #pragma unroll
            for (int m = 0; m < 4; ++m)
                #pragma unroll
                for (int n = 0; n < 2; ++n)
                    acc[m][n] = __builtin_amdgcn_mfma_f32_16x16x32_bf16(
                        av[m], bv[n], acc[m][n], 0, 0, 0);
        }
    };

    // Per-iter issue order: LOAD_H(ck+1) FIRST, then ISSUE_A(ck+2), so the
    // queue at iter ck is [.. H(ck), A(ck+1), H(ck+1), A(ck+2)]: waiting for
    // H(ck)/A(ck) leaves 4+2+4 = 10 newer ops in flight -> VMW(10).
    // Tails: ck=62 -> VMW(6); ck=63 -> VMW(0).
    auto BODY = [&](int ck, const u32x4* hS, u32x4* hL) {
        if (ck + 1 < 64) LOAD_H(hL, (ck + 1) * BK);
        if (ck + 2 < 64) ISSUE_A((ck + 2) % 3, (ck + 2) * BK);
        if (ck < 62)      VMW(10);
        else if (ck == 62) VMW(6);
        else               VMW(0);
        STORE_H(hS);
        RAWBAR;              // H(ck) visible + A(ck) DMA'd for all waves
        MMA(ck % 3);
        RAWBAR;              // all reads of bufA[ck%3]/sH done before reuse
    };

    // prologue: H(0); A(0); A(1)
    LOAD_H(hA, 0);
    ISSUE_A(0, 0);
    ISSUE_A(1, BK);
    #pragma unroll 1
    for (int ck = 0; ck < 64; ck += 2) {
        BODY(ck,     hA, hB);   // stores H(ck) from hA, loads H(ck+1) to hB
        BODY(ck + 1, hB, hA);
    }
    __syncthreads();            // vmcnt already 0; full fence before aliasing

    // ---- epilogue: hn tile -> LDS (C/D layout m89/m91: row=fq*4+r, col=fr)
    #pragma unroll
    for (int m = 0; m < 4; ++m)
        #pragma unroll
        for (int n = 0; n < 2; ++n)
            #pragma unroll
            for (int r = 0; r < 4; ++r)
                sHN[(wm * 64 + m * 16 + fq * 4 + r) * 132
                    + (wn * 32 + n * 16 + fr)] = acc[m][n][r];
    __syncthreads();

    // ---- register-blocked W-gemm + swish (round-0/5/7 proven structure) ----
    const int cg = t & 31;                      // output cols cg*4 .. +3
    const int r0 = (t >> 5) * 8;                // 8 rows per thread
    float aw[8][4];
    #pragma unroll
    for (int r = 0; r < 8; ++r)
        #pragma unroll
        for (int cc = 0; cc < 4; ++cc) aw[r][cc] = 0.f;

    const f4_t* W4 = (const f4_t*)Wm;
    #pragma unroll 4
    for (int k = 0; k < UU; k += 4) {
        const f4_t w0 = W4[(k + 0) * 32 + cg];
        const f4_t w1 = W4[(k + 1) * 32 + cg];
        const f4_t w2 = W4[(k + 2) * 32 + cg];
        const f4_t w3 = W4[(k + 3) * 32 + cg];
        #pragma unroll
        for (int r = 0; r < 8; ++r) {
            const f4_t sv = *(const f4_t*)&sHN[(r0 + r) * 132 + k];
            aw[r][0] += sv[0]*w0[0] + sv[1]*w1[0] + sv[2]*w2[0] + sv[3]*w3[0];
            aw[r][1] += sv[0]*w0[1] + sv[1]*w1[1] + sv[2]*w2[1] + sv[3]*w3[1];
            aw[r][2] += sv[0]*w0[2] + sv[1]*w1[2] + sv[2]*w2[2] + sv[3]*w3[2];
            aw[r][3] += sv[0]*w0[3] + sv[1]*w1[3] + sv[2]*w2[3] + sv[3]*w3[3];
        }
    }

    const f4_t bb4 = ((const f4_t*)bias)[cg];
    #pragma unroll
    for (int r = 0; r < 8; ++r) {
        const size_t row = (size_t)b * NN + i0 + r0 + r;
        float v, o0, o1, o2, o3;
        v = aw[r][0] + bb4[0]; o0 = v / (1.f + expf(-v));
        v = aw[r][1] + bb4[1]; o1 = v / (1.f + expf(-v));
        v = aw[r][2] + bb4[2]; o2 = v / (1.f + expf(-v));
        v = aw[r][3] + bb4[3]; o3 = v / (1.f + expf(-v));
        if (OUT_BF16) {
            u32x2 p;
            p.x = pack2_rne(o0, o1);
            p.y = pack2_rne(o2, o3);
            *(u32x2*)((unsigned short*)dst + row * UU + cg * 4) = p;
        } else {
            f4_t o = {o0, o1, o2, o3};
            *(f4_t*)((float*)dst + row * UU + cg * 4) = o;
        }
    }
}

// ---------------------------------------------------------------------------
extern "C" void kernel_launch(void* const* d_in, const int* in_sizes, int n_in,
                              void* d_out, int out_size, void* d_ws, size_t ws_size,
                              hipStream_t stream)
{
    const float* x    = (const float*)d_in[0];   // [B,N,U] fp32
    const float* adj  = (const float*)d_in[1];   // [B,N,N] binary fp32
    const float* Wm   = (const float*)d_in[2];   // [U,U]
    const float* bias = (const float*)d_in[3];   // [U]
    float* out = (float*)d_out;                  // [B,N,U] fp32

    unsigned short* xb  = (unsigned short*)d_ws;           // 8 MiB bf16 x
    unsigned short* h1b = xb + (size_t)BB * NN * UU;       // 8 MiB bf16 h1

    cvt_bf16_kernel<<<(BB * NN * UU) / (256 * 8), 256, 0, stream>>>(x, xb);

    // Hop 1: swish((adj@xb)@W + b) -> h1 (bf16)
    hop_kernel<1><<<BB * (NN / BM), 512, 0, stream>>>(adj, xb, Wm, bias, (void*)h1b);

    // Hop 2: swish((adj@h1b)@W + b) -> out (fp32)
    hop_kernel<0><<<BB * (NN / BM), 512, 0, stream>>>(adj, h1b, Wm, bias, (void*)out);
}